// Round 17
// baseline (1404.520 us; speedup 1.0000x reference)
//
#include <hip/hip_runtime.h>
#include <hip/hip_bf16.h>

#define V_  32000
#define E_  512
#define H_  1024
#define B_  16
#define T_  256
#define H3  3072

#define AGENT_LD(p)    __hip_atomic_load((p),  __ATOMIC_RELAXED, __HIP_MEMORY_SCOPE_AGENT)
#define AGENT_ST(p, v) __hip_atomic_store((p), (v), __ATOMIC_RELAXED, __HIP_MEMORY_SCOPE_AGENT)

typedef __attribute__((ext_vector_type(8))) _Float16 f16x8;
typedef __attribute__((ext_vector_type(4))) float f32x4;

#define GLDS16(gp, lp) __builtin_amdgcn_global_load_lds( \
    (const __attribute__((address_space(1))) unsigned int*)(gp), \
    (__attribute__((address_space(3))) unsigned int*)(lp), 16, 0, 0)

// ---------------- embedding gather -> fp16 (writes t-major rows) ----------------
__global__ __launch_bounds__(128) void k_embed_f16(const int* __restrict__ x,
                                                   const float* __restrict__ emb,
                                                   _Float16* __restrict__ ef) {
  const int rin = blockIdx.x;                  // b*T + t (x layout)
  const int b = rin >> 8, t = rin & 255;
  const int orow = t * 16 + b;                 // t-major
  const int idx = x[rin];
  const float4 v = ((const float4*)(emb + (size_t)idx * E_))[threadIdx.x];
  _Float16 o[4] = {(_Float16)v.x, (_Float16)v.y, (_Float16)v.z, (_Float16)v.w};
  ushort4 u;
  u.x = *(unsigned short*)&o[0]; u.y = *(unsigned short*)&o[1];
  u.z = *(unsigned short*)&o[2]; u.w = *(unsigned short*)&o[3];
  ((ushort4*)(ef + (size_t)orow * E_))[threadIdx.x] = u;
}

// ---------------- transpose to fp16: W [R][ldw] f32 -> WT [C][R] fp16 ----------------
__global__ __launch_bounds__(256) void k_transpose_f16(const float* __restrict__ W, int ldw,
                                                       _Float16* __restrict__ WT, int R) {
  __shared__ float tile[32][33];
  const int c0 = blockIdx.x * 32, r0 = blockIdx.y * 32;
  const int tx = threadIdx.x & 31, ty = threadIdx.x >> 5;
  #pragma unroll
  for (int i = ty; i < 32; i += 8)
    tile[i][tx] = W[(size_t)(r0 + i) * ldw + c0 + tx];
  __syncthreads();
  #pragma unroll
  for (int i = ty; i < 32; i += 8)
    WT[(size_t)(c0 + i) * R + r0 + tx] = (_Float16)tile[tx][i];
}

// ---------------- bias concat ----------------
__global__ __launch_bounds__(512) void k_catbias(const float* __restrict__ a,
                                                 const float* __restrict__ b,
                                                 float* __restrict__ o) {
  const int i = blockIdx.x * 512 + threadIdx.x;
  o[i] = (i < H3) ? a[i] : b[i - H3];
}

// ---------------- single-pass fp16 MFMA GEMM (GX0 / layer-1 / FC) ----------------
// cfp16: write C as fp16 (layer-1 G1). remap: t-major row -> b-major row (FC logits).
__global__ __launch_bounds__(256, 4) void k_gemm_f16(
    const _Float16* __restrict__ A, const _Float16* __restrict__ BT,
    const float* __restrict__ bias, void* __restrict__ Cv,
    int MT, int NT, int K, int ldc, int remap, int cfp16) {
  __shared__ _Float16 sA[128 * 64], sB[128 * 64];

  const int bid = blockIdx.x;
  const int GROUPM = 8;
  const int group = bid / (GROUPM * NT);
  const int first = group * GROUPM;
  const int gsm = (MT - first < GROUPM) ? (MT - first) : GROUPM;
  const int rem = bid % (GROUPM * NT);
  const int pm = first + rem % gsm;
  const int pn = rem / gsm;
  const int bm = pm * 128, bn = pn * 128;

  const int tid = threadIdx.x;
  const int wv = tid >> 6, l = tid & 63;
  const int wr = wv >> 1, wc = wv & 1;
  const int frow = l & 15;
  const int ksl  = l >> 4;

  f32x4 acc[4][4];
  #pragma unroll
  for (int a = 0; a < 4; ++a)
    #pragma unroll
    for (int b = 0; b < 4; ++b) acc[a][b] = (f32x4){0.f, 0.f, 0.f, 0.f};

  for (int k0 = 0; k0 < K; k0 += 64) {
    __syncthreads();
    #pragma unroll
    for (int p = 0; p < 4; ++p) {
      const int obase = ((p << 2) + wv) << 10;
      const int row = ((obase >> 7)) + (l >> 3);
      const int slot = l & 7;
      const int gcol = k0 + ((slot ^ (row & 7)) << 3);
      GLDS16(A + (size_t)(bm + row) * K + gcol, (char*)sA + obase);
      GLDS16(BT + (size_t)(bn + row) * K + gcol, (char*)sB + obase);
    }
    __syncthreads();
    #pragma unroll
    for (int kk = 0; kk < 2; ++kk) {
      f16x8 a[4], b[4];
      #pragma unroll
      for (int f = 0; f < 4; ++f) {
        const int ar = wr * 64 + f * 16 + frow;
        a[f] = *(const f16x8*)((const char*)sA + ar * 128 + ((((kk << 2) + ksl) ^ (ar & 7)) << 4));
        const int br_ = wc * 64 + f * 16 + frow;
        b[f] = *(const f16x8*)((const char*)sB + br_ * 128 + ((((kk << 2) + ksl) ^ (br_ & 7)) << 4));
      }
      #pragma unroll
      for (int fm = 0; fm < 4; ++fm)
        #pragma unroll
        for (int fn = 0; fn < 4; ++fn)
          acc[fm][fn] = __builtin_amdgcn_mfma_f32_16x16x32_f16(a[fm], b[fn], acc[fm][fn], 0, 0, 0);
    }
  }

  const int crow0 = bm + wr * 64 + (l >> 4) * 4;
  const int ccol0 = bn + wc * 64 + (l & 15);
  #pragma unroll
  for (int fn = 0; fn < 4; ++fn) {
    const int col = ccol0 + fn * 16;
    const float bv = bias[col];
    #pragma unroll
    for (int fm = 0; fm < 4; ++fm) {
      const int r0 = crow0 + fm * 16;
      #pragma unroll
      for (int i = 0; i < 4; ++i) {
        const int rr = r0 + i;
        const int orow = remap ? ((rr & 15) * T_ + (rr >> 4)) : rr;
        const float val = acc[fm][fn][i] + bv;
        if (cfp16) ((_Float16*)Cv)[(size_t)orow * ldc + col] = (_Float16)val;
        else       ((float*)Cv)[(size_t)orow * ldc + col] = val;
      }
    }
  }
}

// ---------------- layer-0 recurrence (round-16 proven, unchanged) ----------------
__global__ __launch_bounds__(512, 1) void k_recur3(
    const _Float16* __restrict__ WhTf,         // [3072][1024] fp16
    const float* __restrict__ GX0,             // [4096][3072] f32, t-major rows
    const float* __restrict__ bh0,
    _Float16* __restrict__ H0f,                // [4096][1024] fp16, t-major
    float* __restrict__ H0last,                // [16][1024] f32 (t = T-1)
    unsigned* __restrict__ bar,
    const float* __restrict__ Wx1,
    const float* __restrict__ Wh1,
    _Float16* __restrict__ BTf) {              // [6144][1024] fp16 (Wx1T|Wh1T)
  __shared__ float red[12288];                 // 48 KB
  const int tid = threadIdx.x;
  const int wg = blockIdx.x;

  if (wg >= 32) {
    // ---------- helper: static-striped Wx1/Wh1 transpose to fp16, then exit ----------
    float* tile = red;                          // [32][33]
    const int ty = tid >> 5, tx = tid & 31;     // ty in [0,16)
    for (int tix = wg - 32; tix < 6144; tix += 224) {
      const int job = tix >= 3072;
      const int tt = job ? tix - 3072 : tix;
      const int c0 = (tt % 96) * 32, r0 = (tt / 96) * 32;
      const float* W = job ? Wh1 : Wx1;
      _Float16* D = BTf + (job ? (size_t)H3 * H_ : 0);
      __syncthreads();
      tile[ty * 33 + tx]        = W[(size_t)(r0 + ty) * H3 + c0 + tx];
      tile[(ty + 16) * 33 + tx] = W[(size_t)(r0 + ty + 16) * H3 + c0 + tx];
      __syncthreads();
      #pragma unroll
      for (int s = 0; s < 2; ++s) {
        const int i = ty + s * 16;
        D[(size_t)(c0 + i) * H_ + r0 + tx] = (_Float16)tile[tx * 33 + i];
      }
    }
    return;
  }

  // ---------- participant WG `rank` owns h-cols [32*rank, 32*rank+32) ----------
  const int rank = wg;
  const int wv = tid >> 6, l = tid & 63;
  const int b  = tid >> 5, jj = tid & 31;
  const int col = rank * 32 + jj;

  // one-time Wh B-frags into VGPRs (fp16, proven frag layout)
  f16x8 breg[6][4];
  #pragma unroll
  for (int nf = 0; nf < 6; ++nf) {
    const int g = nf >> 1, h2 = nf & 1;
    const int bcol = g * 1024 + rank * 32 + h2 * 16 + (l & 15);
    #pragma unroll
    for (int kf = 0; kf < 4; ++kf)
      breg[nf][kf] = *(const f16x8*)(WhTf + (size_t)bcol * 1024 + wv * 128 + kf * 32 + ((l >> 4) << 3));
  }
  const float bhr = bh0[col], bhz = bh0[1024 + col], bhn = bh0[2048 + col];

  float xr, xz, xn;
  {
    const size_t g0 = (size_t)(0 * 16 + b) * H3;
    xr = GX0[g0 + col]; xz = GX0[g0 + 1024 + col]; xn = GX0[g0 + 2048 + col];
  }
  float hprev = 0.f;

  for (int t = 0; t < T_; ++t) {
    f16x8 af[4];
    if (t == 0) {
      #pragma unroll
      for (int kf = 0; kf < 4; ++kf)
        af[kf] = (f16x8){0, 0, 0, 0, 0, 0, 0, 0};
    } else {
      // ---- per-wave dataflow wait ----
      const unsigned* tp = &bar[(unsigned)((4 * wv + (l & 3)) * 32 + rank) * 32];
      int guard = 0;
      for (;;) {
        const unsigned v = AGENT_LD(tp);
        if (__all(v >= (unsigned)t)) break;
        if (++guard > 10000000) break;         // hang guard -> degrade to wrong answer
      }
      // ---- A-frags from H0f plane (t-1 block contiguous 32KB) ----
      const char* ab = (const char*)H0f + (size_t)(t - 1) * 32768 + ((l & 15) * 2048)
                       + ((wv * 128 + ((l >> 4) << 3)) << 1);
      #pragma unroll
      for (int kf = 0; kf < 4; ++kf)
        asm volatile("global_load_dwordx4 %0, %1, off sc0 sc1" : "=v"(af[kf]) : "v"(ab + kf * 64));
      asm volatile("s_waitcnt vmcnt(0)" ::: "memory");
      __builtin_amdgcn_sched_barrier(0);       // RULE #18
    }

    #pragma unroll
    for (int nf = 0; nf < 6; ++nf) {
      f32x4 a4 = (f32x4){0.f, 0.f, 0.f, 0.f};
      #pragma unroll
      for (int kf = 0; kf < 4; ++kf)
        a4 = __builtin_amdgcn_mfma_f32_16x16x32_f16(af[kf], breg[nf][kf], a4, 0, 0, 0);
      *(f32x4*)&red[(((wv * 6 + nf) << 6) + l) << 2] = a4;
    }
    __syncthreads();

    const int h2 = jj >> 4, f = jj & 15;
    const int lp = ((b >> 2) << 4) + f, ii = b & 3;
    float p3[3];
    #pragma unroll
    for (int g = 0; g < 3; ++g) {
      const int nf = g * 2 + h2;
      float s = 0.f;
      #pragma unroll
      for (int w8 = 0; w8 < 8; ++w8)
        s += red[((((w8 * 6 + nf) << 6) + lp) << 2) + ii];
      p3[g] = s;
    }
    const float r = 1.f / (1.f + expf(-(xr + p3[0] + bhr)));
    const float z = 1.f / (1.f + expf(-(xz + p3[1] + bhz)));
    const float n = tanhf(xn + r * (p3[2] + bhn));
    const float hnew = (1.f - z) * n + z * hprev;
    hprev = hnew;

    {
      const _Float16 hf = (_Float16)hnew;
      const unsigned tmp = (unsigned)*(const unsigned short*)&hf;
      const unsigned nb = __shfl_xor(tmp, 1);
      if ((jj & 1) == 0) {
        const unsigned w = (tmp & 0xffffu) | (nb << 16);
        const size_t u32i = (((size_t)(t * 16 + b) << 10) + col) >> 1;
        AGENT_ST((unsigned*)H0f + u32i, w);
      }
    }
    if (t == T_ - 1) H0last[(b << 10) + col] = hnew;

    if (t + 1 < T_) {
      __syncthreads();                         // vmcnt(0) drain: h stores at LLC
      if (tid < 32) AGENT_ST(&bar[(unsigned)(rank * 32 + tid) * 32], (unsigned)(t + 1));
      {
        const size_t g0 = (size_t)((t + 1) * 16 + b) * H3;
        xr = GX0[g0 + col]; xz = GX0[g0 + 1024 + col]; xn = GX0[g0 + 2048 + col];
      }
    }
  }
}

// ---------------- layer-1 elementwise: fp16 gates + fp16 h0 in, fp16 H1 out ----------------
__global__ __launch_bounds__(256) void k_gru1(const _Float16* __restrict__ G1f,
                                              const _Float16* __restrict__ H0f,
                                              _Float16* __restrict__ H1f,
                                              float* __restrict__ H1last, int row0) {
  const int lrow = blockIdx.x;
  const int row = row0 + lrow;                 // t-major
  const _Float16* g = G1f + (size_t)lrow * 6144;
  for (int j = threadIdx.x; j < H_; j += 256) {
    const float xr = (float)g[j], xz = (float)g[1024 + j], xn = (float)g[2048 + j];
    const float hr = (float)g[3072 + j], hz = (float)g[4096 + j], hn = (float)g[5120 + j];
    const size_t idx = ((size_t)row << 10) + j;
    const float h = (float)H0f[idx];
    const float r = 1.f / (1.f + expf(-(xr + hr)));
    const float z = 1.f / (1.f + expf(-(xz + hz)));
    const float n = tanhf(xn + r * hn);
    const float hnew = (1.f - z) * n + z * h;
    H1f[idx] = (_Float16)hnew;
    if (row >= 4080) H1last[((row - 4080) << 10) + j] = hnew;
  }
}

// ---------------- final hidden: out[2][B][H] from f32 last-step buffers ----------------
__global__ __launch_bounds__(256) void k_hidden(const float* __restrict__ H0last,
                                                const float* __restrict__ H1last,
                                                float* __restrict__ out) {
  const int i = blockIdx.x * 256 + threadIdx.x;
  const int l = i >> 14;
  const int bj = i & 16383;
  out[i] = l ? H1last[bj] : H0last[bj];
}

extern "C" void kernel_launch(void* const* d_in, const int* in_sizes, int n_in,
                              void* d_out, int out_size, void* d_ws, size_t ws_size,
                              hipStream_t stream) {
  const int*   x   = (const int*)d_in[0];
  const float* emb = (const float*)d_in[1];
  const float* Wx0 = (const float*)d_in[2];
  const float* Wh0 = (const float*)d_in[3];
  const float* bx0 = (const float*)d_in[4];
  const float* bh0 = (const float*)d_in[5];
  const float* Wx1 = (const float*)d_in[6];
  const float* Wh1 = (const float*)d_in[7];
  const float* bx1 = (const float*)d_in[8];
  const float* bh1 = (const float*)d_in[9];
  const float* fcW = (const float*)d_in[10];
  const float* fcb = (const float*)d_in[11];
  float* out = (float*)d_out;

  char* ws = (char*)d_ws;
  const size_t MB = 1024 * 1024;
  // persistent hidden states (t-major rows)
  _Float16* H0f    = (_Float16*)(ws + 0);                  // 8 MB [4096][1024] fp16
  _Float16* H1f    = (_Float16*)(ws + 8 * MB);             // 8 MB
  float*    H0last = (float*)(ws + 16 * MB);               // 64 KB f32 [16][1024]
  float*    H1last = (float*)(ws + 16 * MB + 65536);       // 64 KB
  char* S = ws + 32 * MB;
  // phase A/B
  _Float16* WhTf  = (_Float16*)(S);                        // 6 MB [3072][1024] fp16
  float*    GX0   = (float*)(S + 8 * MB);                  // 48 MB (t-major)
  _Float16* EmbF  = (_Float16*)(S + 56 * MB);              // 4 MB [4096][512] (dead after GX0)
  _Float16* Wx0Tf = (_Float16*)(S + 60 * MB);              // 3 MB [3072][512] (dead after GX0)
  // written by helper WGs during k_recur3 (over the corpses above):
  _Float16* BTf   = (_Float16*)(S + 56 * MB);              // 12 MB [6144][1024] fp16
  unsigned* bar   = (unsigned*)(S + 80 * MB);              // 128 KB tag matrix
  float*    b1cat = (float*)(S + 80 * MB + 131072);        // 24 KB
  // phase C (GX0 corpse)
  _Float16* G1f = (_Float16*)(S + 8 * MB);                 // 24 MB [2048][6144] fp16
  // phase D (whole S corpse)
  _Float16* fcTf = (_Float16*)(S);                         // 31.25 MB [16000][1024] fp16

  // ---- phase A: embed->fp16 (t-major), Wh0/Wx0 fp16 transposes, GX0 via fp16 MFMA ----
  k_embed_f16<<<dim3(B_ * T_), dim3(128), 0, stream>>>(x, emb, EmbF);
  k_transpose_f16<<<dim3(H3 / 32, H_ / 32), dim3(256), 0, stream>>>(Wh0, H3, WhTf, H_);
  k_transpose_f16<<<dim3(H3 / 32, E_ / 32), dim3(256), 0, stream>>>(Wx0, H3, Wx0Tf, E_);
  k_gemm_f16<<<dim3(32 * 24), dim3(256), 0, stream>>>(
      EmbF, Wx0Tf, bx0, GX0, 32, 24, E_, H3, 0, 0);
  k_catbias<<<dim3(12), dim3(512), 0, stream>>>(bx1, bh1, b1cat);

  // ---- phase B: recurrence (WGs 0-31) + Wx1/Wh1 fp16 transposes (WGs 32-255) ----
  hipMemsetAsync(bar, 0, 131072, stream);
  {
    void* args[] = {(void*)&WhTf, (void*)&GX0, (void*)&bh0, (void*)&H0f, (void*)&H0last,
                    (void*)&bar, (void*)&Wx1, (void*)&Wh1, (void*)&BTf};
    hipLaunchCooperativeKernel((const void*)k_recur3, dim3(256), dim3(512), args, 0, stream);
  }

  // ---- phase C: layer 1, one fp16 GEMM per chunk (N = 6144, fp16 G1) ----
  for (int chunk = 0; chunk < 2; ++chunk) {
    const _Float16* Ac = H0f + (size_t)chunk * 2048 * H_;
    k_gemm_f16<<<dim3(16 * 48), dim3(256), 0, stream>>>(
        Ac, BTf, b1cat, G1f, 16, 48, H_, 6144, 0, 1);
    k_gru1<<<dim3(2048), dim3(256), 0, stream>>>(G1f, H0f, H1f, H1last, chunk * 2048);
  }

  // ---- phase D: FC via fp16 MFMA, 2 N-chunks of 16000, b-major epilogue remap ----
  for (int chunk = 0; chunk < 2; ++chunk) {
    const float* Wc = fcW + (size_t)chunk * 16000;
    k_transpose_f16<<<dim3(16000 / 32, H_ / 32), dim3(256), 0, stream>>>(Wc, V_, fcTf, H_);
    k_gemm_f16<<<dim3(32 * 125), dim3(256), 0, stream>>>(
        H1f, fcTf, fcb + (size_t)chunk * 16000,
        out + (size_t)chunk * 16000, 32, 125, H_, V_, 1, 0);
  }

  // ---- final hidden ----
  k_hidden<<<dim3(32768 / 256), dim3(256), 0, stream>>>(H0last, H1last,
                                                        out + (size_t)B_ * T_ * V_);
}

// Round 18
// 1400.520 us; speedup vs baseline: 1.0029x; 1.0029x over previous
//
#include <hip/hip_runtime.h>
#include <hip/hip_bf16.h>

#define V_  32000
#define E_  512
#define H_  1024
#define B_  16
#define T_  256
#define H3  3072

#define AGENT_ST(p, v) __hip_atomic_store((p), (v), __ATOMIC_RELAXED, __HIP_MEMORY_SCOPE_AGENT)
#define SENT 0x7F7F7F7Fu   // 2x fp16 NaN (0x7F7F) -- unreachable by finite gate math

typedef __attribute__((ext_vector_type(8))) _Float16 f16x8;
typedef __attribute__((ext_vector_type(4))) float f32x4;

#define GLDS16(gp, lp) __builtin_amdgcn_global_load_lds( \
    (const __attribute__((address_space(1))) unsigned int*)(gp), \
    (__attribute__((address_space(3))) unsigned int*)(lp), 16, 0, 0)

// ---------------- embedding gather -> fp16 (writes t-major rows) ----------------
__global__ __launch_bounds__(128) void k_embed_f16(const int* __restrict__ x,
                                                   const float* __restrict__ emb,
                                                   _Float16* __restrict__ ef) {
  const int rin = blockIdx.x;                  // b*T + t (x layout)
  const int b = rin >> 8, t = rin & 255;
  const int orow = t * 16 + b;                 // t-major
  const int idx = x[rin];
  const float4 v = ((const float4*)(emb + (size_t)idx * E_))[threadIdx.x];
  _Float16 o[4] = {(_Float16)v.x, (_Float16)v.y, (_Float16)v.z, (_Float16)v.w};
  ushort4 u;
  u.x = *(unsigned short*)&o[0]; u.y = *(unsigned short*)&o[1];
  u.z = *(unsigned short*)&o[2]; u.w = *(unsigned short*)&o[3];
  ((ushort4*)(ef + (size_t)orow * E_))[threadIdx.x] = u;
}

// ---------------- transpose to fp16: W [R][ldw] f32 -> WT [C][R] fp16 ----------------
__global__ __launch_bounds__(256) void k_transpose_f16(const float* __restrict__ W, int ldw,
                                                       _Float16* __restrict__ WT, int R) {
  __shared__ float tile[32][33];
  const int c0 = blockIdx.x * 32, r0 = blockIdx.y * 32;
  const int tx = threadIdx.x & 31, ty = threadIdx.x >> 5;
  #pragma unroll
  for (int i = ty; i < 32; i += 8)
    tile[i][tx] = W[(size_t)(r0 + i) * ldw + c0 + tx];
  __syncthreads();
  #pragma unroll
  for (int i = ty; i < 32; i += 8)
    WT[(size_t)(c0 + i) * R + r0 + tx] = (_Float16)tile[tx][i];
}

// ---------------- bias concat ----------------
__global__ __launch_bounds__(512) void k_catbias(const float* __restrict__ a,
                                                 const float* __restrict__ b,
                                                 float* __restrict__ o) {
  const int i = blockIdx.x * 512 + threadIdx.x;
  o[i] = (i < H3) ? a[i] : b[i - H3];
}

// ---------------- single-pass fp16 MFMA GEMM (GX0 / layer-1 / FC) ----------------
__global__ __launch_bounds__(256, 4) void k_gemm_f16(
    const _Float16* __restrict__ A, const _Float16* __restrict__ BT,
    const float* __restrict__ bias, void* __restrict__ Cv,
    int MT, int NT, int K, int ldc, int remap, int cfp16) {
  __shared__ _Float16 sA[128 * 64], sB[128 * 64];

  const int bid = blockIdx.x;
  const int GROUPM = 8;
  const int group = bid / (GROUPM * NT);
  const int first = group * GROUPM;
  const int gsm = (MT - first < GROUPM) ? (MT - first) : GROUPM;
  const int rem = bid % (GROUPM * NT);
  const int pm = first + rem % gsm;
  const int pn = rem / gsm;
  const int bm = pm * 128, bn = pn * 128;

  const int tid = threadIdx.x;
  const int wv = tid >> 6, l = tid & 63;
  const int wr = wv >> 1, wc = wv & 1;
  const int frow = l & 15;
  const int ksl  = l >> 4;

  f32x4 acc[4][4];
  #pragma unroll
  for (int a = 0; a < 4; ++a)
    #pragma unroll
    for (int b = 0; b < 4; ++b) acc[a][b] = (f32x4){0.f, 0.f, 0.f, 0.f};

  for (int k0 = 0; k0 < K; k0 += 64) {
    __syncthreads();
    #pragma unroll
    for (int p = 0; p < 4; ++p) {
      const int obase = ((p << 2) + wv) << 10;
      const int row = ((obase >> 7)) + (l >> 3);
      const int slot = l & 7;
      const int gcol = k0 + ((slot ^ (row & 7)) << 3);
      GLDS16(A + (size_t)(bm + row) * K + gcol, (char*)sA + obase);
      GLDS16(BT + (size_t)(bn + row) * K + gcol, (char*)sB + obase);
    }
    __syncthreads();
    #pragma unroll
    for (int kk = 0; kk < 2; ++kk) {
      f16x8 a[4], b[4];
      #pragma unroll
      for (int f = 0; f < 4; ++f) {
        const int ar = wr * 64 + f * 16 + frow;
        a[f] = *(const f16x8*)((const char*)sA + ar * 128 + ((((kk << 2) + ksl) ^ (ar & 7)) << 4));
        const int br_ = wc * 64 + f * 16 + frow;
        b[f] = *(const f16x8*)((const char*)sB + br_ * 128 + ((((kk << 2) + ksl) ^ (br_ & 7)) << 4));
      }
      #pragma unroll
      for (int fm = 0; fm < 4; ++fm)
        #pragma unroll
        for (int fn = 0; fn < 4; ++fn)
          acc[fm][fn] = __builtin_amdgcn_mfma_f32_16x16x32_f16(a[fm], b[fn], acc[fm][fn], 0, 0, 0);
    }
  }

  const int crow0 = bm + wr * 64 + (l >> 4) * 4;
  const int ccol0 = bn + wc * 64 + (l & 15);
  #pragma unroll
  for (int fn = 0; fn < 4; ++fn) {
    const int col = ccol0 + fn * 16;
    const float bv = bias[col];
    #pragma unroll
    for (int fm = 0; fm < 4; ++fm) {
      const int r0 = crow0 + fm * 16;
      #pragma unroll
      for (int i = 0; i < 4; ++i) {
        const int rr = r0 + i;
        const int orow = remap ? ((rr & 15) * T_ + (rr >> 4)) : rr;
        const float val = acc[fm][fn][i] + bv;
        if (cfp16) ((_Float16*)Cv)[(size_t)orow * ldc + col] = (_Float16)val;
        else       ((float*)Cv)[(size_t)orow * ldc + col] = val;
      }
    }
  }
}

// ---------------- layer-0 recurrence: sentinel dataflow (no tags) ----------------
// H0f pre-memset to 0x7F bytes (fp16 NaN sentinel). Producers publish h as packed-pair
// u32 AGENT_STs (word-atomic: each u32 is sentinel or final). Consumers poll their own
// A-frag words via sc0/sc1 loads until no word == SENT. RAW gated by content; WAR
// vacuous (t-major, each block written once). RULE #18 fence after accepted loads.
// Helper WGs (32..255) transpose Wx1/Wh1 (+ fcW when doFC) under the recurrence shadow.
__global__ __launch_bounds__(512, 1) void k_recur3(
    const _Float16* __restrict__ WhTf,         // [3072][1024] fp16
    const float* __restrict__ GX0,             // [4096][3072] f32, t-major rows
    const float* __restrict__ bh0,
    _Float16* __restrict__ H0f,                // [4096][1024] fp16, t-major (sentinel-filled)
    float* __restrict__ H0last,                // [16][1024] f32 (t = T-1)
    const float* __restrict__ Wx1,
    const float* __restrict__ Wh1,
    _Float16* __restrict__ BTf,                // [6144][1024] fp16 (Wx1T|Wh1T)
    const float* __restrict__ fcW,
    _Float16* __restrict__ fcTf,               // [32000][1024] fp16 (when doFC)
    int doFC) {
  __shared__ float red[12288];                 // 48 KB
  const int tid = threadIdx.x;
  const int wg = blockIdx.x;

  if (wg >= 32) {
    // ---------- helper: static-striped transposes to fp16, then exit ----------
    float* tile = red;                          // [32][33]
    const int ty = tid >> 5, tx = tid & 31;     // ty in [0,16)
    const int total = doFC ? (6144 + 32000) : 6144;
    for (int tix = wg - 32; tix < total; tix += 224) {
      const float* W;
      _Float16* D;
      int c0, r0, ldw;
      if (tix < 6144) {
        const int job = tix >= 3072;
        const int tt = job ? tix - 3072 : tix;
        c0 = (tt % 96) * 32; r0 = (tt / 96) * 32;
        W = job ? Wh1 : Wx1;
        D = BTf + (job ? (size_t)H3 * H_ : 0);
        ldw = H3;
      } else {
        const int tt = tix - 6144;              // fcW [1024][32000] -> fcTf [32000][1024]
        c0 = (tt % 1000) * 32; r0 = (tt / 1000) * 32;
        W = fcW; D = fcTf; ldw = V_;
      }
      __syncthreads();
      tile[ty * 33 + tx]        = W[(size_t)(r0 + ty) * ldw + c0 + tx];
      tile[(ty + 16) * 33 + tx] = W[(size_t)(r0 + ty + 16) * ldw + c0 + tx];
      __syncthreads();
      #pragma unroll
      for (int s = 0; s < 2; ++s) {
        const int i = ty + s * 16;
        D[(size_t)(c0 + i) * H_ + r0 + tx] = (_Float16)tile[tx * 33 + i];
      }
    }
    return;
  }

  // ---------- participant WG `rank` owns h-cols [32*rank, 32*rank+32) ----------
  const int rank = wg;
  const int wv = tid >> 6, l = tid & 63;
  const int b  = tid >> 5, jj = tid & 31;
  const int col = rank * 32 + jj;

  // one-time Wh B-frags into VGPRs (fp16, proven frag layout)
  f16x8 breg[6][4];
  #pragma unroll
  for (int nf = 0; nf < 6; ++nf) {
    const int g = nf >> 1, h2 = nf & 1;
    const int bcol = g * 1024 + rank * 32 + h2 * 16 + (l & 15);
    #pragma unroll
    for (int kf = 0; kf < 4; ++kf)
      breg[nf][kf] = *(const f16x8*)(WhTf + (size_t)bcol * 1024 + wv * 128 + kf * 32 + ((l >> 4) << 3));
  }
  const float bhr = bh0[col], bhz = bh0[1024 + col], bhn = bh0[2048 + col];

  float xr, xz, xn;
  {
    const size_t g0 = (size_t)(0 * 16 + b) * H3;
    xr = GX0[g0 + col]; xz = GX0[g0 + 1024 + col]; xn = GX0[g0 + 2048 + col];
  }
  float hprev = 0.f;

  for (int t = 0; t < T_; ++t) {
    f16x8 af[4];
    if (t == 0) {
      #pragma unroll
      for (int kf = 0; kf < 4; ++kf)
        af[kf] = (f16x8){0, 0, 0, 0, 0, 0, 0, 0};
    } else {
      // ---- sentinel poll: load A-frags until no word is the NaN sentinel ----
      const char* ab = (const char*)H0f + (size_t)(t - 1) * 32768 + ((l & 15) * 2048)
                       + ((wv * 128 + ((l >> 4) << 3)) << 1);
      int guard = 0;
      bool ok;
      do {
        #pragma unroll
        for (int kf = 0; kf < 4; ++kf)
          asm volatile("global_load_dwordx4 %0, %1, off sc0 sc1" : "=v"(af[kf]) : "v"(ab + kf * 64));
        asm volatile("s_waitcnt vmcnt(0)" ::: "memory");
        ok = true;
        #pragma unroll
        for (int kf = 0; kf < 4; ++kf) {
          const uint4 u = *(const uint4*)&af[kf];
          ok = ok && (u.x != SENT) && (u.y != SENT) && (u.z != SENT) && (u.w != SENT);
        }
      } while (!__all(ok) && ++guard < 10000000);   // guard -> degrade to wrong answer
      __builtin_amdgcn_sched_barrier(0);            // RULE #18: MFMA must not hoist
    }

    #pragma unroll
    for (int nf = 0; nf < 6; ++nf) {
      f32x4 a4 = (f32x4){0.f, 0.f, 0.f, 0.f};
      #pragma unroll
      for (int kf = 0; kf < 4; ++kf)
        a4 = __builtin_amdgcn_mfma_f32_16x16x32_f16(af[kf], breg[nf][kf], a4, 0, 0, 0);
      *(f32x4*)&red[(((wv * 6 + nf) << 6) + l) << 2] = a4;
    }
    __syncthreads();

    const int h2 = jj >> 4, f = jj & 15;
    const int lp = ((b >> 2) << 4) + f, ii = b & 3;
    float p3[3];
    #pragma unroll
    for (int g = 0; g < 3; ++g) {
      const int nf = g * 2 + h2;
      float s = 0.f;
      #pragma unroll
      for (int w8 = 0; w8 < 8; ++w8)
        s += red[((((w8 * 6 + nf) << 6) + lp) << 2) + ii];
      p3[g] = s;
    }
    const float r = 1.f / (1.f + expf(-(xr + p3[0] + bhr)));
    const float z = 1.f / (1.f + expf(-(xz + p3[1] + bhz)));
    const float n = tanhf(xn + r * (p3[2] + bhn));
    const float hnew = (1.f - z) * n + z * hprev;
    hprev = hnew;

    // ---- publish h (packed fp16 col-pairs, word-atomic AGENT_ST) ----
    {
      const _Float16 hf = (_Float16)hnew;
      const unsigned tmp = (unsigned)*(const unsigned short*)&hf;
      const unsigned nb = __shfl_xor(tmp, 1);
      if ((jj & 1) == 0) {
        const unsigned w = (tmp & 0xffffu) | (nb << 16);
        const size_t u32i = (((size_t)(t * 16 + b) << 10) + col) >> 1;
        AGENT_ST((unsigned*)H0f + u32i, w);
      }
    }
    if (t == T_ - 1) H0last[(b << 10) + col] = hnew;

    if (t + 1 < T_) {
      __syncthreads();                         // red-buffer reuse gate (intra-WG)
      {                                        // GX0 prefetch overlaps next poll
        const size_t g0 = (size_t)((t + 1) * 16 + b) * H3;
        xr = GX0[g0 + col]; xz = GX0[g0 + 1024 + col]; xn = GX0[g0 + 2048 + col];
      }
    }
  }
}

// ---------------- layer-1 elementwise: fp16 gates + fp16 h0 in, fp16 H1 out ----------------
__global__ __launch_bounds__(256) void k_gru1(const _Float16* __restrict__ G1f,
                                              const _Float16* __restrict__ H0f,
                                              _Float16* __restrict__ H1f,
                                              float* __restrict__ H1last, int row0) {
  const int lrow = blockIdx.x;
  const int row = row0 + lrow;                 // t-major
  const _Float16* g = G1f + (size_t)lrow * 6144;
  for (int j = threadIdx.x; j < H_; j += 256) {
    const float xr = (float)g[j], xz = (float)g[1024 + j], xn = (float)g[2048 + j];
    const float hr = (float)g[3072 + j], hz = (float)g[4096 + j], hn = (float)g[5120 + j];
    const size_t idx = ((size_t)row << 10) + j;
    const float h = (float)H0f[idx];
    const float r = 1.f / (1.f + expf(-(xr + hr)));
    const float z = 1.f / (1.f + expf(-(xz + hz)));
    const float n = tanhf(xn + r * hn);
    const float hnew = (1.f - z) * n + z * h;
    H1f[idx] = (_Float16)hnew;
    if (row >= 4080) H1last[((row - 4080) << 10) + j] = hnew;
  }
}

// ---------------- final hidden: out[2][B][H] from f32 last-step buffers ----------------
__global__ __launch_bounds__(256) void k_hidden(const float* __restrict__ H0last,
                                                const float* __restrict__ H1last,
                                                float* __restrict__ out) {
  const int i = blockIdx.x * 256 + threadIdx.x;
  const int l = i >> 14;
  const int bj = i & 16383;
  out[i] = l ? H1last[bj] : H0last[bj];
}

extern "C" void kernel_launch(void* const* d_in, const int* in_sizes, int n_in,
                              void* d_out, int out_size, void* d_ws, size_t ws_size,
                              hipStream_t stream) {
  const int*   x   = (const int*)d_in[0];
  const float* emb = (const float*)d_in[1];
  const float* Wx0 = (const float*)d_in[2];
  const float* Wh0 = (const float*)d_in[3];
  const float* bx0 = (const float*)d_in[4];
  const float* bh0 = (const float*)d_in[5];
  const float* Wx1 = (const float*)d_in[6];
  const float* Wh1 = (const float*)d_in[7];
  const float* bx1 = (const float*)d_in[8];
  const float* bh1 = (const float*)d_in[9];
  const float* fcW = (const float*)d_in[10];
  const float* fcb = (const float*)d_in[11];
  float* out = (float*)d_out;

  char* ws = (char*)d_ws;
  const size_t MB = 1024 * 1024;
  // persistent hidden states (t-major rows)
  _Float16* H0f    = (_Float16*)(ws + 0);                  // 8 MB [4096][1024] fp16
  _Float16* H1f    = (_Float16*)(ws + 8 * MB);             // 8 MB
  float*    H0last = (float*)(ws + 16 * MB);               // 64 KB f32 [16][1024]
  float*    H1last = (float*)(ws + 16 * MB + 65536);       // 64 KB
  char* S = ws + 32 * MB;
  // phase A/B
  _Float16* WhTf  = (_Float16*)(S);                        // 6 MB [3072][1024] fp16
  float*    GX0   = (float*)(S + 8 * MB);                  // 48 MB (t-major)
  _Float16* EmbF  = (_Float16*)(S + 56 * MB);              // 4 MB (dead after GX0)
  _Float16* Wx0Tf = (_Float16*)(S + 60 * MB);              // 3 MB (dead after GX0)
  // written by helper WGs during k_recur3 (over the corpses above):
  _Float16* BTf   = (_Float16*)(S + 56 * MB);              // 12 MB [6144][1024] fp16
  float*    b1cat = (float*)(S + 80 * MB);                 // 24 KB
  _Float16* fcTfB = (_Float16*)(S + 82 * MB);              // 62.5 MB [32000][1024] (doFC)
  // phase C (GX0 corpse)
  _Float16* G1f = (_Float16*)(S + 8 * MB);                 // 24 MB [2048][6144] fp16
  // phase D fallback (whole S corpse)
  _Float16* fcTf1 = (_Float16*)(S);                        // 31.25 MB [16000][1024]

  const int doFC = (ws_size >= (size_t)190 * MB) ? 1 : 0;

  // ---- phase A: embed->fp16 (t-major), Wh0/Wx0 fp16 transposes, GX0 via fp16 MFMA ----
  k_embed_f16<<<dim3(B_ * T_), dim3(128), 0, stream>>>(x, emb, EmbF);
  k_transpose_f16<<<dim3(H3 / 32, H_ / 32), dim3(256), 0, stream>>>(Wh0, H3, WhTf, H_);
  k_transpose_f16<<<dim3(H3 / 32, E_ / 32), dim3(256), 0, stream>>>(Wx0, H3, Wx0Tf, E_);
  k_gemm_f16<<<dim3(32 * 24), dim3(256), 0, stream>>>(
      EmbF, Wx0Tf, bx0, GX0, 32, 24, E_, H3, 0, 0);
  k_catbias<<<dim3(12), dim3(512), 0, stream>>>(bx1, bh1, b1cat);

  // ---- phase B: sentinel-fill H0f, recurrence (WGs 0-31) + transposes (WGs 32-255) ----
  hipMemsetAsync(H0f, 0x7F, 8 * MB, stream);   // fp16 NaN sentinel per u16
  {
    void* args[] = {(void*)&WhTf, (void*)&GX0, (void*)&bh0, (void*)&H0f, (void*)&H0last,
                    (void*)&Wx1, (void*)&Wh1, (void*)&BTf,
                    (void*)&fcW, (void*)&fcTfB, (void*)&doFC};
    hipLaunchCooperativeKernel((const void*)k_recur3, dim3(256), dim3(512), args, 0, stream);
  }

  // ---- phase C: layer 1, one fp16 GEMM per chunk (N = 6144, fp16 G1) ----
  for (int chunk = 0; chunk < 2; ++chunk) {
    const _Float16* Ac = H0f + (size_t)chunk * 2048 * H_;
    k_gemm_f16<<<dim3(16 * 48), dim3(256), 0, stream>>>(
        Ac, BTf, b1cat, G1f, 16, 48, H_, 6144, 0, 1);
    k_gru1<<<dim3(2048), dim3(256), 0, stream>>>(G1f, H0f, H1f, H1last, chunk * 2048);
  }

  // ---- phase D: FC via fp16 MFMA ----
  if (doFC) {
    // fcTfB was filled by helper WGs under the recurrence shadow: one launch, N=32000
    k_gemm_f16<<<dim3(32 * 250), dim3(256), 0, stream>>>(
        H1f, fcTfB, fcb, out, 32, 250, H_, V_, 1, 0);
  } else {
    for (int chunk = 0; chunk < 2; ++chunk) {
      const float* Wc = fcW + (size_t)chunk * 16000;
      k_transpose_f16<<<dim3(16000 / 32, H_ / 32), dim3(256), 0, stream>>>(Wc, V_, fcTf1, H_);
      k_gemm_f16<<<dim3(32 * 125), dim3(256), 0, stream>>>(
          H1f, fcTf1, fcb + (size_t)chunk * 16000,
          out + (size_t)chunk * 16000, 32, 125, H_, V_, 1, 0);
    }
  }

  // ---- final hidden ----
  k_hidden<<<dim3(32768 / 256), dim3(256), 0, stream>>>(H0last, H1last,
                                                        out + (size_t)B_ * T_ * V_);
}

// Round 19
// 1389.263 us; speedup vs baseline: 1.0110x; 1.0081x over previous
//
#include <hip/hip_runtime.h>
#include <hip/hip_bf16.h>

#define V_  32000
#define E_  512
#define H_  1024
#define B_  16
#define T_  256
#define H3  3072

#define AGENT_ST(p, v) __hip_atomic_store((p), (v), __ATOMIC_RELAXED, __HIP_MEMORY_SCOPE_AGENT)
#define SENT 0x7F7F7F7Fu   // 2x fp16 NaN (0x7F7F) -- unreachable by finite gate math

typedef __attribute__((ext_vector_type(8))) _Float16 f16x8;
typedef __attribute__((ext_vector_type(4))) float f32x4;

#define GLDS16(gp, lp) __builtin_amdgcn_global_load_lds( \
    (const __attribute__((address_space(1))) unsigned int*)(gp), \
    (__attribute__((address_space(3))) unsigned int*)(lp), 16, 0, 0)

// ---------------- embedding gather -> fp16 (writes t-major rows) ----------------
__global__ __launch_bounds__(128) void k_embed_f16(const int* __restrict__ x,
                                                   const float* __restrict__ emb,
                                                   _Float16* __restrict__ ef) {
  const int rin = blockIdx.x;                  // b*T + t (x layout)
  const int b = rin >> 8, t = rin & 255;
  const int orow = t * 16 + b;                 // t-major
  const int idx = x[rin];
  const float4 v = ((const float4*)(emb + (size_t)idx * E_))[threadIdx.x];
  _Float16 o[4] = {(_Float16)v.x, (_Float16)v.y, (_Float16)v.z, (_Float16)v.w};
  ushort4 u;
  u.x = *(unsigned short*)&o[0]; u.y = *(unsigned short*)&o[1];
  u.z = *(unsigned short*)&o[2]; u.w = *(unsigned short*)&o[3];
  ((ushort4*)(ef + (size_t)orow * E_))[threadIdx.x] = u;
}

// ---------------- transpose to fp16: W [R][ldw] f32 -> WT [C][R] fp16 ----------------
__global__ __launch_bounds__(256) void k_transpose_f16(const float* __restrict__ W, int ldw,
                                                       _Float16* __restrict__ WT, int R) {
  __shared__ float tile[32][33];
  const int c0 = blockIdx.x * 32, r0 = blockIdx.y * 32;
  const int tx = threadIdx.x & 31, ty = threadIdx.x >> 5;
  #pragma unroll
  for (int i = ty; i < 32; i += 8)
    tile[i][tx] = W[(size_t)(r0 + i) * ldw + c0 + tx];
  __syncthreads();
  #pragma unroll
  for (int i = ty; i < 32; i += 8)
    WT[(size_t)(c0 + i) * R + r0 + tx] = (_Float16)tile[tx][i];
}

// ---------------- bias concat ----------------
__global__ __launch_bounds__(512) void k_catbias(const float* __restrict__ a,
                                                 const float* __restrict__ b,
                                                 float* __restrict__ o) {
  const int i = blockIdx.x * 512 + threadIdx.x;
  o[i] = (i < H3) ? a[i] : b[i - H3];
}

// ---------------- single-pass fp16 MFMA GEMM (GX0 / layer-1 / FC) ----------------
__global__ __launch_bounds__(256, 4) void k_gemm_f16(
    const _Float16* __restrict__ A, const _Float16* __restrict__ BT,
    const float* __restrict__ bias, void* __restrict__ Cv,
    int MT, int NT, int K, int ldc, int remap, int cfp16) {
  __shared__ _Float16 sA[128 * 64], sB[128 * 64];

  const int bid = blockIdx.x;
  const int GROUPM = 8;
  const int group = bid / (GROUPM * NT);
  const int first = group * GROUPM;
  const int gsm = (MT - first < GROUPM) ? (MT - first) : GROUPM;
  const int rem = bid % (GROUPM * NT);
  const int pm = first + rem % gsm;
  const int pn = rem / gsm;
  const int bm = pm * 128, bn = pn * 128;

  const int tid = threadIdx.x;
  const int wv = tid >> 6, l = tid & 63;
  const int wr = wv >> 1, wc = wv & 1;
  const int frow = l & 15;
  const int ksl  = l >> 4;

  f32x4 acc[4][4];
  #pragma unroll
  for (int a = 0; a < 4; ++a)
    #pragma unroll
    for (int b = 0; b < 4; ++b) acc[a][b] = (f32x4){0.f, 0.f, 0.f, 0.f};

  for (int k0 = 0; k0 < K; k0 += 64) {
    __syncthreads();
    #pragma unroll
    for (int p = 0; p < 4; ++p) {
      const int obase = ((p << 2) + wv) << 10;
      const int row = ((obase >> 7)) + (l >> 3);
      const int slot = l & 7;
      const int gcol = k0 + ((slot ^ (row & 7)) << 3);
      GLDS16(A + (size_t)(bm + row) * K + gcol, (char*)sA + obase);
      GLDS16(BT + (size_t)(bn + row) * K + gcol, (char*)sB + obase);
    }
    __syncthreads();
    #pragma unroll
    for (int kk = 0; kk < 2; ++kk) {
      f16x8 a[4], b[4];
      #pragma unroll
      for (int f = 0; f < 4; ++f) {
        const int ar = wr * 64 + f * 16 + frow;
        a[f] = *(const f16x8*)((const char*)sA + ar * 128 + ((((kk << 2) + ksl) ^ (ar & 7)) << 4));
        const int br_ = wc * 64 + f * 16 + frow;
        b[f] = *(const f16x8*)((const char*)sB + br_ * 128 + ((((kk << 2) + ksl) ^ (br_ & 7)) << 4));
      }
      #pragma unroll
      for (int fm = 0; fm < 4; ++fm)
        #pragma unroll
        for (int fn = 0; fn < 4; ++fn)
          acc[fm][fn] = __builtin_amdgcn_mfma_f32_16x16x32_f16(a[fm], b[fn], acc[fm][fn], 0, 0, 0);
    }
  }

  const int crow0 = bm + wr * 64 + (l >> 4) * 4;
  const int ccol0 = bn + wc * 64 + (l & 15);
  #pragma unroll
  for (int fn = 0; fn < 4; ++fn) {
    const int col = ccol0 + fn * 16;
    const float bv = bias[col];
    #pragma unroll
    for (int fm = 0; fm < 4; ++fm) {
      const int r0 = crow0 + fm * 16;
      #pragma unroll
      for (int i = 0; i < 4; ++i) {
        const int rr = r0 + i;
        const int orow = remap ? ((rr & 15) * T_ + (rr >> 4)) : rr;
        const float val = acc[fm][fn][i] + bv;
        if (cfp16) ((_Float16*)Cv)[(size_t)orow * ldc + col] = (_Float16)val;
        else       ((float*)Cv)[(size_t)orow * ldc + col] = val;
      }
    }
  }
}

// ---------------- layer-0 recurrence: sentinel dataflow (round-18 proven) ----------------
__global__ __launch_bounds__(512, 1) void k_recur3(
    const _Float16* __restrict__ WhTf,         // [3072][1024] fp16
    const float* __restrict__ GX0,             // [4096][3072] f32, t-major rows
    const float* __restrict__ bh0,
    _Float16* __restrict__ H0f,                // [4096][1024] fp16, t-major (sentinel-filled)
    float* __restrict__ H0last,                // [16][1024] f32 -> d_out hidden slot 0
    const float* __restrict__ Wx1,
    const float* __restrict__ Wh1,
    _Float16* __restrict__ BTf,                // [6144][1024] fp16 (Wx1T|Wh1T)
    const float* __restrict__ fcW,
    _Float16* __restrict__ fcTf,               // [32000][1024] fp16 (when doFC)
    int doFC) {
  __shared__ float red[12288];                 // 48 KB
  const int tid = threadIdx.x;
  const int wg = blockIdx.x;

  if (wg >= 32) {
    // ---------- helper: static-striped transposes to fp16, then exit ----------
    float* tile = red;                          // [32][33]
    const int ty = tid >> 5, tx = tid & 31;     // ty in [0,16)
    const int total = doFC ? (6144 + 32000) : 6144;
    for (int tix = wg - 32; tix < total; tix += 224) {
      const float* W;
      _Float16* D;
      int c0, r0, ldw;
      if (tix < 6144) {
        const int job = tix >= 3072;
        const int tt = job ? tix - 3072 : tix;
        c0 = (tt % 96) * 32; r0 = (tt / 96) * 32;
        W = job ? Wh1 : Wx1;
        D = BTf + (job ? (size_t)H3 * H_ : 0);
        ldw = H3;
      } else {
        const int tt = tix - 6144;              // fcW [1024][32000] -> fcTf [32000][1024]
        c0 = (tt % 1000) * 32; r0 = (tt / 1000) * 32;
        W = fcW; D = fcTf; ldw = V_;
      }
      __syncthreads();
      tile[ty * 33 + tx]        = W[(size_t)(r0 + ty) * ldw + c0 + tx];
      tile[(ty + 16) * 33 + tx] = W[(size_t)(r0 + ty + 16) * ldw + c0 + tx];
      __syncthreads();
      #pragma unroll
      for (int s = 0; s < 2; ++s) {
        const int i = ty + s * 16;
        D[(size_t)(c0 + i) * H_ + r0 + tx] = (_Float16)tile[tx * 33 + i];
      }
    }
    return;
  }

  // ---------- participant WG `rank` owns h-cols [32*rank, 32*rank+32) ----------
  const int rank = wg;
  const int wv = tid >> 6, l = tid & 63;
  const int b  = tid >> 5, jj = tid & 31;
  const int col = rank * 32 + jj;

  // one-time Wh B-frags into VGPRs (fp16, proven frag layout)
  f16x8 breg[6][4];
  #pragma unroll
  for (int nf = 0; nf < 6; ++nf) {
    const int g = nf >> 1, h2 = nf & 1;
    const int bcol = g * 1024 + rank * 32 + h2 * 16 + (l & 15);
    #pragma unroll
    for (int kf = 0; kf < 4; ++kf)
      breg[nf][kf] = *(const f16x8*)(WhTf + (size_t)bcol * 1024 + wv * 128 + kf * 32 + ((l >> 4) << 3));
  }
  const float bhr = bh0[col], bhz = bh0[1024 + col], bhn = bh0[2048 + col];

  float xr, xz, xn;
  {
    const size_t g0 = (size_t)(0 * 16 + b) * H3;
    xr = GX0[g0 + col]; xz = GX0[g0 + 1024 + col]; xn = GX0[g0 + 2048 + col];
  }
  float hprev = 0.f;

  for (int t = 0; t < T_; ++t) {
    f16x8 af[4];
    if (t == 0) {
      #pragma unroll
      for (int kf = 0; kf < 4; ++kf)
        af[kf] = (f16x8){0, 0, 0, 0, 0, 0, 0, 0};
    } else {
      // ---- sentinel poll: load A-frags until no word is the NaN sentinel ----
      const char* ab = (const char*)H0f + (size_t)(t - 1) * 32768 + ((l & 15) * 2048)
                       + ((wv * 128 + ((l >> 4) << 3)) << 1);
      int guard = 0;
      bool ok;
      do {
        #pragma unroll
        for (int kf = 0; kf < 4; ++kf)
          asm volatile("global_load_dwordx4 %0, %1, off sc0 sc1" : "=v"(af[kf]) : "v"(ab + kf * 64));
        asm volatile("s_waitcnt vmcnt(0)" ::: "memory");
        ok = true;
        #pragma unroll
        for (int kf = 0; kf < 4; ++kf) {
          const uint4 u = *(const uint4*)&af[kf];
          ok = ok && (u.x != SENT) && (u.y != SENT) && (u.z != SENT) && (u.w != SENT);
        }
      } while (!__all(ok) && ++guard < 10000000);   // guard -> degrade to wrong answer
      __builtin_amdgcn_sched_barrier(0);            // RULE #18: MFMA must not hoist
    }

    #pragma unroll
    for (int nf = 0; nf < 6; ++nf) {
      f32x4 a4 = (f32x4){0.f, 0.f, 0.f, 0.f};
      #pragma unroll
      for (int kf = 0; kf < 4; ++kf)
        a4 = __builtin_amdgcn_mfma_f32_16x16x32_f16(af[kf], breg[nf][kf], a4, 0, 0, 0);
      *(f32x4*)&red[(((wv * 6 + nf) << 6) + l) << 2] = a4;
    }
    __syncthreads();

    const int h2 = jj >> 4, f = jj & 15;
    const int lp = ((b >> 2) << 4) + f, ii = b & 3;
    float p3[3];
    #pragma unroll
    for (int g = 0; g < 3; ++g) {
      const int nf = g * 2 + h2;
      float s = 0.f;
      #pragma unroll
      for (int w8 = 0; w8 < 8; ++w8)
        s += red[((((w8 * 6 + nf) << 6) + lp) << 2) + ii];
      p3[g] = s;
    }
    const float r = 1.f / (1.f + expf(-(xr + p3[0] + bhr)));
    const float z = 1.f / (1.f + expf(-(xz + p3[1] + bhz)));
    const float n = tanhf(xn + r * (p3[2] + bhn));
    const float hnew = (1.f - z) * n + z * hprev;
    hprev = hnew;

    // ---- publish h (packed fp16 col-pairs, word-atomic AGENT_ST) ----
    {
      const _Float16 hf = (_Float16)hnew;
      const unsigned tmp = (unsigned)*(const unsigned short*)&hf;
      const unsigned nb = __shfl_xor(tmp, 1);
      if ((jj & 1) == 0) {
        const unsigned w = (tmp & 0xffffu) | (nb << 16);
        const size_t u32i = (((size_t)(t * 16 + b) << 10) + col) >> 1;
        AGENT_ST((unsigned*)H0f + u32i, w);
      }
    }
    if (t == T_ - 1) H0last[(b << 10) + col] = hnew;

    if (t + 1 < T_) {
      __syncthreads();                         // red-buffer reuse gate (intra-WG)
      {                                        // GX0 prefetch overlaps next poll
        const size_t g0 = (size_t)((t + 1) * 16 + b) * H3;
        xr = GX0[g0 + col]; xz = GX0[g0 + 1024 + col]; xn = GX0[g0 + 2048 + col];
      }
    }
  }
}

// ---------------- layer-1 elementwise: fp16 gates + fp16 h0 in, fp16 H1 out ----------------
__global__ __launch_bounds__(256) void k_gru1(const _Float16* __restrict__ G1f,
                                              const _Float16* __restrict__ H0f,
                                              _Float16* __restrict__ H1f,
                                              float* __restrict__ H1last) {
  const int row = blockIdx.x;                  // t-major, 0..4095
  const _Float16* g = G1f + (size_t)row * 6144;
  for (int j = threadIdx.x; j < H_; j += 256) {
    const float xr = (float)g[j], xz = (float)g[1024 + j], xn = (float)g[2048 + j];
    const float hr = (float)g[3072 + j], hz = (float)g[4096 + j], hn = (float)g[5120 + j];
    const size_t idx = ((size_t)row << 10) + j;
    const float h = (float)H0f[idx];
    const float r = 1.f / (1.f + expf(-(xr + hr)));
    const float z = 1.f / (1.f + expf(-(xz + hz)));
    const float n = tanhf(xn + r * hn);
    const float hnew = (1.f - z) * n + z * h;
    H1f[idx] = (_Float16)hnew;
    if (row >= 4080) H1last[((row - 4080) << 10) + j] = hnew;  // f32 final h1 -> d_out
  }
}

extern "C" void kernel_launch(void* const* d_in, const int* in_sizes, int n_in,
                              void* d_out, int out_size, void* d_ws, size_t ws_size,
                              hipStream_t stream) {
  const int*   x   = (const int*)d_in[0];
  const float* emb = (const float*)d_in[1];
  const float* Wx0 = (const float*)d_in[2];
  const float* Wh0 = (const float*)d_in[3];
  const float* bx0 = (const float*)d_in[4];
  const float* bh0 = (const float*)d_in[5];
  const float* Wx1 = (const float*)d_in[6];
  const float* Wh1 = (const float*)d_in[7];
  const float* bx1 = (const float*)d_in[8];
  const float* bh1 = (const float*)d_in[9];
  const float* fcW = (const float*)d_in[10];
  const float* fcb = (const float*)d_in[11];
  float* out = (float*)d_out;

  char* ws = (char*)d_ws;
  const size_t MB = 1024 * 1024;
  // persistent hidden states (t-major rows)
  _Float16* H0f = (_Float16*)(ws + 0);                     // 8 MB [4096][1024] fp16
  _Float16* H1f = (_Float16*)(ws + 8 * MB);                // 8 MB
  // final hidden written straight into d_out
  float* H0last = out + (size_t)B_ * T_ * V_;              // [16][1024] f32
  float* H1last = H0last + 16384;
  char* S = ws + 32 * MB;
  // phase A/B
  _Float16* WhTf  = (_Float16*)(S);                        // 6 MB [3072][1024] fp16
  float*    GX0   = (float*)(S + 8 * MB);                  // 48 MB (t-major)
  _Float16* EmbF  = (_Float16*)(S + 56 * MB);              // 4 MB (dead after GX0)
  _Float16* Wx0Tf = (_Float16*)(S + 60 * MB);              // 3 MB (dead after GX0)
  // written by helper WGs during k_recur3 (over the corpses above):
  _Float16* BTf   = (_Float16*)(S + 56 * MB);              // 12 MB [6144][1024] fp16
  float*    b1cat = (float*)(S + 80 * MB);                 // 24 KB
  _Float16* fcTfB = (_Float16*)(S + 82 * MB);              // 62.5 MB [32000][1024] (doFC)
  // phase C (GX0 corpse, full 48 MB now)
  _Float16* G1f = (_Float16*)(S + 8 * MB);                 // 48 MB [4096][6144] fp16
  // phase D fallback (whole S corpse)
  _Float16* fcTf1 = (_Float16*)(S);                        // 31.25 MB [16000][1024]

  const int doFC = (ws_size >= (size_t)190 * MB) ? 1 : 0;

  // ---- phase A: embed->fp16 (t-major), Wh0/Wx0 fp16 transposes, GX0 via fp16 MFMA ----
  k_embed_f16<<<dim3(B_ * T_), dim3(128), 0, stream>>>(x, emb, EmbF);
  k_transpose_f16<<<dim3(H3 / 32, H_ / 32), dim3(256), 0, stream>>>(Wh0, H3, WhTf, H_);
  k_transpose_f16<<<dim3(H3 / 32, E_ / 32), dim3(256), 0, stream>>>(Wx0, H3, Wx0Tf, E_);
  k_gemm_f16<<<dim3(32 * 24), dim3(256), 0, stream>>>(
      EmbF, Wx0Tf, bx0, GX0, 32, 24, E_, H3, 0, 0);
  k_catbias<<<dim3(12), dim3(512), 0, stream>>>(bx1, bh1, b1cat);

  // ---- phase B: sentinel-fill H0f, recurrence (WGs 0-31) + transposes (WGs 32-255) ----
  hipMemsetAsync(H0f, 0x7F, 8 * MB, stream);   // fp16 NaN sentinel per u16
  {
    void* args[] = {(void*)&WhTf, (void*)&GX0, (void*)&bh0, (void*)&H0f, (void*)&H0last,
                    (void*)&Wx1, (void*)&Wh1, (void*)&BTf,
                    (void*)&fcW, (void*)&fcTfB, (void*)&doFC};
    hipLaunchCooperativeKernel((const void*)k_recur3, dim3(256), dim3(512), args, 0, stream);
  }

  // ---- phase C: layer 1, ONE fp16 GEMM (M=4096, N=6144) + ONE gru1 ----
  k_gemm_f16<<<dim3(32 * 48), dim3(256), 0, stream>>>(
      H0f, BTf, b1cat, G1f, 32, 48, H_, 6144, 0, 1);
  k_gru1<<<dim3(4096), dim3(256), 0, stream>>>(G1f, H0f, H1f, H1last);

  // ---- phase D: FC via fp16 MFMA ----
  if (doFC) {
    k_gemm_f16<<<dim3(32 * 250), dim3(256), 0, stream>>>(
        H1f, fcTfB, fcb, out, 32, 250, H_, V_, 1, 0);
  } else {
    for (int chunk = 0; chunk < 2; ++chunk) {
      const float* Wc = fcW + (size_t)chunk * 16000;
      k_transpose_f16<<<dim3(16000 / 32, H_ / 32), dim3(256), 0, stream>>>(Wc, V_, fcTf1, H_);
      k_gemm_f16<<<dim3(32 * 125), dim3(256), 0, stream>>>(
          H1f, fcTf1, fcb + (size_t)chunk * 16000,
          out + (size_t)chunk * 16000, 32, 125, H_, V_, 1, 0);
    }
  }
}